// Round 7
// baseline (134.526 us; speedup 1.0000x reference)
//
#include <hip/hip_runtime.h>
#include <hip/hip_bf16.h>

typedef __attribute__((ext_vector_type(8))) short bf16x8;
typedef __attribute__((ext_vector_type(4))) float f32x4;

#define F_DIM 128
#define N_DIM 20000
#define M_DIM 128
#define NW 32                 // n per tile
#define TILES_PER_B 625       // 20000/32
#define NT 20                 // tiles per block
#define GRID 500              // 500*20 = 10000 tiles
#define F32_TILE 32768        // per-tile f32 stage: 2 mats * 128f * 32n * 4B
#define F32_MAT 16384
#define BF16_OFF 65536        // after 2 f32 buffers
#define BF16_MAT 8192

#define AS1 __attribute__((address_space(1)))
#define AS3 __attribute__((address_space(3)))

static __device__ inline unsigned short f2bf(float x) {
    union { float f; unsigned u; } v; v.f = x;
    unsigned r = v.u + 0x7fffu + ((v.u >> 16) & 1u);   // RNE
    return (unsigned short)(r >> 16);
}

static __device__ inline unsigned cvt_pk_bf16(float lo, float hi) {
    unsigned r;
    asm("v_cvt_pk_bf16_f32 %0, %1, %2" : "=v"(r) : "v"(lo), "v"(hi));
    return r;
}

// ---------------------------------------------------------------------------
// Kernel 1: fold resize into projections; bf16 in MFMA fragment order.
// ---------------------------------------------------------------------------
__global__ __launch_bounds__(256) void precompute_mats(
    const float* __restrict__ W_rs,   // (128, 384)
    const float* __restrict__ W_e2m,  // (128, 128)
    const float* __restrict__ W_n2m,  // (128, 128)
    unsigned short* __restrict__ wsA,
    unsigned short* __restrict__ wsB)
{
    int idx = blockIdx.x * 256 + threadIdx.x;   // 0..16383
    int k = idx >> 7;
    int f = idx & 127;
    float a = 0.f, b = 0.f;
    for (int m = 0; m < 128; ++m) {
        a += W_rs[k * 384 + m]       * W_e2m[m * 128 + f];
        b += W_rs[k * 384 + 128 + m] * W_n2m[m * 128 + f];
    }
    int mt = k >> 4, row = k & 15;
    int c = f >> 5, kk = f & 31;
    int lane = ((kk >> 3) << 4) | row;
    int j = kk & 7;
    int off = ((mt * 4 + c) * 64 + lane) * 8 + j;
    wsA[off] = f2bf(a);
    wsB[off] = f2bf(b);
}

// ---------------------------------------------------------------------------
// Kernel 2: per-(b,k) bias.
// ---------------------------------------------------------------------------
__global__ __launch_bounds__(128) void precompute_bias(
    const float* __restrict__ W_rs,
    const float* __restrict__ h_v,
    const float* __restrict__ b_e2m,
    const float* __restrict__ b_n2m,
    const float* __restrict__ b_rs,
    const float* __restrict__ W_n2m,
    float* __restrict__ bias)
{
    __shared__ float nv_s[128];
    int b = blockIdx.x;
    int t = threadIdx.x;
    {
        float nv = b_n2m[t];
        for (int f = 0; f < 128; ++f)
            nv += h_v[b * 128 + f] * W_n2m[t * 128 + f];
        nv_s[t] = nv;
    }
    __syncthreads();
    {
        float acc = b_rs[t];
        for (int m = 0; m < 128; ++m) {
            acc += W_rs[t * 384 + m]       * b_e2m[m];
            acc += W_rs[t * 384 + 128 + m] * b_n2m[m];
            acc += W_rs[t * 384 + 256 + m] * nv_s[m];
        }
        bias[b * 128 + t] = acc;
    }
}

// ---------------------------------------------------------------------------
// Kernel 3: persistent pipelined streaming GEMM.
// Per-wave VMEM queue per iter (in order): [bias 2][DMA(t+2) 8] ... prior
// iter left [DMA(t+1) 8][stores(t-1) 16]. "DMA(t+1) done" == vmcnt<=24
// (8 for t==0). Stores/bias retire OFF the critical path. Last two DMA
// slots are lane-uniform dummies (L2-hit) to keep counts uniform w/o wrap.
// ---------------------------------------------------------------------------
__global__ __launch_bounds__(256, 2) void msg_main(
    const float* __restrict__ e_wv,
    const float* __restrict__ h_w,
    const unsigned short* __restrict__ wsA,
    const unsigned short* __restrict__ wsB,
    const float* __restrict__ bias,
    float* __restrict__ out)
{
    __shared__ __align__(16) unsigned char smem[81920];   // 2x32KB f32 + 16KB bf16

    int tid = threadIdx.x;
    int w   = tid >> 6;
    int l   = tid & 63;
    unsigned base = (unsigned)blockIdx.x * NT;

    // ---- preload weight fragments (loop-invariant, 64 VGPR)
    const bf16x8* Af = (const bf16x8*)wsA;
    const bf16x8* Bf = (const bf16x8*)wsB;
    bf16x8 A0[4], A1[4], B0[4], B1[4];
#pragma unroll
    for (int c = 0; c < 4; ++c) {
        A0[c] = Af[((2 * w + 0) * 4 + c) * 64 + l];
        A1[c] = Af[((2 * w + 1) * 4 + c) * 64 + l];
        B0[c] = Bf[((2 * w + 0) * 4 + c) * 64 + l];
        B1[c] = Bf[((2 * w + 1) * 4 + c) * 64 + l];
    }

    int fl = l >> 3, p = l & 7;
    auto issue_dma = [&](unsigned tau, unsigned bufsel) {
        unsigned bb = tau / TILES_PER_B;
        unsigned n0 = (tau - bb * TILES_PER_B) * NW;
        const float* eb = e_wv + (size_t)bb * (F_DIM * (size_t)N_DIM) + n0;
        const float* wp = h_w  + (size_t)bb * (F_DIM * (size_t)N_DIM) + n0;
        unsigned char* buf = smem + bufsel * F32_TILE;
#pragma unroll
        for (int i = 0; i < 4; ++i) {
            int fb = i * 32 + w * 8;
            int f  = fb + fl;
            int g  = (f ^ (f >> 3)) & 7;
            int col = (p ^ g) << 2;
            __builtin_amdgcn_global_load_lds(
                (const AS1 unsigned*)(eb + (size_t)f * N_DIM + col),
                (AS3 unsigned*)(buf + fb * 128), 16, 0, 0);
            __builtin_amdgcn_global_load_lds(
                (const AS1 unsigned*)(wp + (size_t)f * N_DIM + col),
                (AS3 unsigned*)(buf + F32_MAT + fb * 128), 16, 0, 0);
        }
    };

    // lane-uniform dummy DMAs: keep per-wave vmcnt counts identical on the
    // last two iterations without re-fetching wrapped tiles (L2-hit, ~free).
    auto issue_dma_dummy = [&](unsigned bufsel) {
        unsigned char* buf = smem + bufsel * F32_TILE;
#pragma unroll
        for (int i = 0; i < 4; ++i) {
            int fb = i * 32 + w * 8;
            __builtin_amdgcn_global_load_lds(
                (const AS1 unsigned*)e_wv,
                (AS3 unsigned*)(buf + fb * 128), 16, 0, 0);
            __builtin_amdgcn_global_load_lds(
                (const AS1 unsigned*)h_w,
                (AS3 unsigned*)(buf + F32_MAT + fb * 128), 16, 0, 0);
        }
    };

    auto transform = [&](unsigned bufsel) {
        const unsigned char* fsrc = smem + bufsel * F32_TILE + (tid >> 7) * F32_MAT;
        unsigned char* bdst = smem + BF16_OFF + (tid >> 7) * BF16_MAT;
        int u = tid & 127;
        int fp = u >> 1, half = u & 1;
        int f0 = 2 * fp, f1 = 2 * fp + 1;
        int g0 = (f0 ^ (f0 >> 3)) & 7, g1 = (f1 ^ (f1 >> 3)) & 7;
#pragma unroll
        for (int j = 0; j < 4; ++j) {
            int q = half * 4 + j;
            f32x4 a = *(const f32x4*)(fsrc + f0 * 128 + ((q ^ g0) << 4));
            f32x4 c = *(const f32x4*)(fsrc + f1 * 128 + ((q ^ g1) << 4));
#pragma unroll
            for (int e = 0; e < 4; ++e) {
                int n = q * 4 + e;
                unsigned pk = cvt_pk_bf16(a[e], c[e]);   // lo=f0, hi=f1
                unsigned off = (unsigned)(n * 256) +
                               (((unsigned)(fp * 4)) ^ ((unsigned)((n & 7) << 4)));
                *(unsigned*)(bdst + off) = pk;
            }
        }
    };

    // ---- prologue: DMA tiles 0,1; transform tile 0
    issue_dma(base + 0, 0);
    issue_dma(base + 1, 1);
    asm volatile("s_waitcnt vmcnt(8)" ::: "memory");   // weights + DMA(0) done
    __builtin_amdgcn_s_barrier();
    transform(0);
    asm volatile("s_waitcnt lgkmcnt(0)" ::: "memory");
    __builtin_amdgcn_s_barrier();

    int ln = l & 15, g = l >> 4;
    unsigned rbase = (unsigned)(ln * 256);
    unsigned rx = (unsigned)((ln & 7) << 4);
    const unsigned char* ldse = smem + BF16_OFF;
    const unsigned char* ldsw = smem + BF16_OFF + BF16_MAT;

#pragma unroll 1
    for (int t = 0; t < NT; ++t) {
        unsigned tau = base + t;
        unsigned bb = tau / TILES_PER_B;
        unsigned n0 = (tau - bb * TILES_PER_B) * NW;

        // bias for this tile (compiler inserts its own exact-counted wait)
        const float* bp = bias + bb * 128;
        f32x4 bv0 = *(const f32x4*)(bp + (2 * w + 0) * 16 + g * 4);
        f32x4 bv1 = *(const f32x4*)(bp + (2 * w + 1) * 16 + g * 4);

        // issue DMA for tile t+2 into buf[t&1] (dummy on last two iters)
        if (t < NT - 2) issue_dma(base + t + 2, (unsigned)(t & 1));
        else            issue_dma_dummy((unsigned)(t & 1));

        // compute(t) from bf16 buffer
        f32x4 acc[2][2];
#pragma unroll
        for (int mtL = 0; mtL < 2; ++mtL)
#pragma unroll
            for (int ns = 0; ns < 2; ++ns) acc[mtL][ns] = (f32x4)(0.f);
#pragma unroll
        for (int c = 0; c < 4; ++c) {
            unsigned fbyte = (unsigned)((c * 32 + g * 8) * 2) ^ rx;
#pragma unroll
            for (int ns = 0; ns < 2; ++ns) {
                bf16x8 xe = *(const bf16x8*)(ldse + ns * 4096 + rbase + fbyte);
                bf16x8 xw = *(const bf16x8*)(ldsw + ns * 4096 + rbase + fbyte);
                acc[0][ns] = __builtin_amdgcn_mfma_f32_16x16x32_bf16(A0[c], xe, acc[0][ns], 0, 0, 0);
                acc[0][ns] = __builtin_amdgcn_mfma_f32_16x16x32_bf16(B0[c], xw, acc[0][ns], 0, 0, 0);
                acc[1][ns] = __builtin_amdgcn_mfma_f32_16x16x32_bf16(A1[c], xe, acc[1][ns], 0, 0, 0);
                acc[1][ns] = __builtin_amdgcn_mfma_f32_16x16x32_bf16(B1[c], xw, acc[1][ns], 0, 0, 0);
            }
        }

        // counted wait: DMA(t+1) retired <=> outstanding <= 24
        // (queue after DMA(t+1): stores(t-1) 16 + bias(t) 2 + DMA(t+2) 8;
        //  t==0 has no prior stores -> 8). Stores stay outstanding.
        if (t == 0) { asm volatile("s_waitcnt vmcnt(8)"  ::: "memory"); }
        else        { asm volatile("s_waitcnt vmcnt(24)" ::: "memory"); }
        asm volatile("s_waitcnt lgkmcnt(0)" ::: "memory");
        __builtin_amdgcn_s_barrier();

        if (t < NT - 1) transform((unsigned)((t + 1) & 1));
        asm volatile("s_waitcnt lgkmcnt(0)" ::: "memory");
        __builtin_amdgcn_s_barrier();

        // store(t): bias + plain dword stores (L2 merges 64B halves)
        float* O = out + (size_t)bb * (M_DIM * (size_t)N_DIM) + n0 + ln;
#pragma unroll
        for (int mtL = 0; mtL < 2; ++mtL) {
            f32x4 bv = mtL ? bv1 : bv0;
            int mt = 2 * w + mtL;
#pragma unroll
            for (int ns = 0; ns < 2; ++ns)
#pragma unroll
                for (int r = 0; r < 4; ++r)
                    O[(size_t)(mt * 16 + g * 4 + r) * N_DIM + ns * 16] =
                        acc[mtL][ns][r] + bv[r];
        }
    }

    // drain outstanding DMAs before endpgm (LDS reuse hazard)
    asm volatile("s_waitcnt vmcnt(0)" ::: "memory");
}

extern "C" void kernel_launch(void* const* d_in, const int* in_sizes, int n_in,
                              void* d_out, int out_size, void* d_ws, size_t ws_size,
                              hipStream_t stream) {
    const float* h_w   = (const float*)d_in[0];
    const float* h_v   = (const float*)d_in[1];
    const float* e_wv  = (const float*)d_in[2];
    const float* W_e2m = (const float*)d_in[3];
    const float* b_e2m = (const float*)d_in[4];
    const float* W_n2m = (const float*)d_in[5];
    const float* b_n2m = (const float*)d_in[6];
    const float* W_rs  = (const float*)d_in[7];
    const float* b_rs  = (const float*)d_in[8];
    float* out = (float*)d_out;

    unsigned short* wsA = (unsigned short*)d_ws;                     // 32 KB
    unsigned short* wsB = wsA + 128 * 128;                           // 32 KB
    float* bias = (float*)((char*)d_ws + 65536);                     // 8 KB

    precompute_mats<<<64, 256, 0, stream>>>(W_rs, W_e2m, W_n2m, wsA, wsB);
    precompute_bias<<<16, 128, 0, stream>>>(W_rs, h_v, b_e2m, b_n2m, b_rs, W_n2m, bias);
    msg_main<<<GRID, 256, 0, stream>>>(e_wv, h_w, wsA, wsB, bias, out);
}